// Round 10
// baseline (12236.934 us; speedup 1.0000x reference)
//
#include <hip/hip_runtime.h>
#include <stdint.h>

#define Bn 128
#define Tn 128
#define En 512
#define Hn 384
#define Zn 128
#define ZHn 256
#define NSTEPS 127

typedef float f32x4 __attribute__((ext_vector_type(4)));

__device__ __forceinline__ float sigm(float x){ return 1.0f/(1.0f + expf(-x)); }

__device__ __forceinline__ void dot4(const float* __restrict__ x,
    const float* __restrict__ w0, const float* __restrict__ w1,
    const float* __restrict__ w2, const float* __restrict__ w3, int K,
    float& a0, float& a1, float& a2, float& a3)
{
  for(int kk = 0; kk < K; kk += 4){
    f32x4 xv = *(const f32x4*)(x + kk);
    f32x4 v0 = *(const f32x4*)(w0 + kk);
    f32x4 v1 = *(const f32x4*)(w1 + kk);
    f32x4 v2 = *(const f32x4*)(w2 + kk);
    f32x4 v3 = *(const f32x4*)(w3 + kk);
    #pragma unroll
    for(int e = 0; e < 4; ++e){
      float xf = xv[e];
      a0 += xf * v0[e];
      a1 += xf * v1[e];
      a2 += xf * v2[e];
      a3 += xf * v3[e];
    }
  }
}

__device__ __forceinline__ float dot1(const float* __restrict__ x,
    const float* __restrict__ w, int K)
{
  float a = 0.f;
  for(int kk = 0; kk < K; kk += 4){
    f32x4 xv = *(const f32x4*)(x + kk);
    f32x4 wv = *(const f32x4*)(w + kk);
    #pragma unroll
    for(int e = 0; e < 4; ++e) a += xv[e] * wv[e];
  }
  return a;
}

// ---------------- sticky active flag: active(s) = all columns t'<=s+1 nonzero ----
__global__ __launch_bounds__(128) void k_act(const int* __restrict__ seq,
                                             int* __restrict__ act)
{
  __shared__ int nz[128];
  int t = threadIdx.x;
  if(t >= 1){
    long long s = 0;
    for(int b = 0; b < Bn; ++b) s += seq[b*Tn + t];
    nz[t] = (s != 0);
  }
  __syncthreads();
  if(t == 0){
    int sticky = 1;
    for(int s = 0; s < NSTEPS; ++s){ sticky = sticky && nz[s+1]; act[s] = sticky; }
  }
}

// ---------------- pipelined step: L0(k) on WGs 0..191, L1(k-1) on 192..383 ------
// WG covers 128 batch rows x 2 hidden units; thread -> (b = tid&127, j).
__global__ __launch_bounds__(256) void k_stepV(int k, const int* __restrict__ seq,
    const float* __restrict__ embed,
    const float* __restrict__ Wih0, const float* __restrict__ Whh0,
    const float* __restrict__ Wih1, const float* __restrict__ Whh1,
    float* __restrict__ h0a, float* __restrict__ h0b,
    float* __restrict__ h1a, float* __restrict__ h1b,
    float* __restrict__ c0s, float* __restrict__ c1s,
    const int* __restrict__ act)
{
  int wg = blockIdx.x;
  int isL1 = wg >= 192;
  int lu = isL1 ? wg - 192 : wg;
  int tid = threadIdx.x;
  int b = tid & 127;
  int j = lu*2 + (tid >> 7);
  int s = isL1 ? k - 1 : k;
  if (s < 0 || s >= NSTEPS) return;

  const float *hin0, *hin1 = nullptr;
  float *hout; float* cbuf;
  if(!isL1){
    int p = s & 1;                 // h0(even s)->h0b, h0(odd s)->h0a
    hin0 = p ? h0b : h0a;          // h0(s-1)
    hout = p ? h0a : h0b;          // h0(s)
    cbuf = c0s;
  } else {
    hin0 = (k & 1) ? h0b : h0a;    // nh0(s), written by previous launch's L0
    int q = s & 1;
    hin1 = q ? h1b : h1a;          // h1(s-1)
    hout = q ? h1a : h1b;          // h1(s)
    cbuf = c1s;
  }

  if(!act[s]){
    const float* src = isL1 ? hin1 : hin0;   // freeze: carry state forward
    hout[b*Hn + j] = src[b*Hn + j];
    return;
  }

  float a0 = 0.f, a1 = 0.f, a2 = 0.f, a3 = 0.f;   // gates i,f,g,o

  if(!isL1){
    int tok = seq[b*Tn + (s+1)];
    if((unsigned)tok > 30000u) tok = 0;           // defensive clamp
    dot4(embed + (size_t)tok * En,
         Wih0 + (size_t)(0*Hn + j) * En, Wih0 + (size_t)(1*Hn + j) * En,
         Wih0 + (size_t)(2*Hn + j) * En, Wih0 + (size_t)(3*Hn + j) * En,
         En, a0, a1, a2, a3);
    dot4(hin0 + b*Hn,
         Whh0 + (size_t)(0*Hn + j) * Hn, Whh0 + (size_t)(1*Hn + j) * Hn,
         Whh0 + (size_t)(2*Hn + j) * Hn, Whh0 + (size_t)(3*Hn + j) * Hn,
         Hn, a0, a1, a2, a3);
  } else {
    dot4(hin0 + b*Hn,
         Wih1 + (size_t)(0*Hn + j) * Hn, Wih1 + (size_t)(1*Hn + j) * Hn,
         Wih1 + (size_t)(2*Hn + j) * Hn, Wih1 + (size_t)(3*Hn + j) * Hn,
         Hn, a0, a1, a2, a3);
    dot4(hin1 + b*Hn,
         Whh1 + (size_t)(0*Hn + j) * Hn, Whh1 + (size_t)(1*Hn + j) * Hn,
         Whh1 + (size_t)(2*Hn + j) * Hn, Whh1 + (size_t)(3*Hn + j) * Hn,
         Hn, a0, a1, a2, a3);
  }

  float cp = cbuf[b*Hn + j];
  float cc = sigm(a1)*cp + sigm(a0)*tanhf(a2);
  float hh = sigm(a3)*tanhf(cc);
  cbuf[b*Hn + j] = cc;
  hout[b*Hn + j] = hh;
}

// ---------------- VAE head: hv = relu(h1 @ W1^T + b1) ----------------
__global__ __launch_bounds__(256) void k_headAV(const float* __restrict__ h1,
    const float* __restrict__ W1, const float* __restrict__ b1,
    float* __restrict__ hv)
{
  int tid = threadIdx.x;
  int b = tid & 127;
  int col = blockIdx.x*2 + (tid >> 7);           // 0..255
  float a = dot1(h1 + b*Hn, W1 + (size_t)col*Hn, Hn) + b1[col];
  hv[b*ZHn + col] = a > 0.f ? a : 0.f;
}

// mu -> out f32 [0:16384), lv -> out f32 [16384:32768); also f32 scratch for z
__global__ __launch_bounds__(256) void k_headB3(const float* __restrict__ hv,
    const float* __restrict__ Wmu, const float* __restrict__ bmu,
    const float* __restrict__ Wlv, const float* __restrict__ blv,
    float* __restrict__ muf, float* __restrict__ lvf, float* __restrict__ out)
{
  int tid = threadIdx.x;
  int b = tid & 127;
  int o = blockIdx.x*2 + (tid >> 7);             // 0..255: [0,128)=mu, rest lv
  int head = o >> 7, hr = o & 127;
  const float* W = head ? Wlv : Wmu;
  float a = dot1(hv + b*ZHn, W + (size_t)hr*ZHn, ZHn) + (head ? blv : bmu)[hr];
  if(head){ lvf[b*Zn + hr] = a; out[16384 + b*Zn + hr] = a; }
  else    { muf[b*Zn + hr] = a; out[         b*Zn + hr] = a; }
}

// concat: out f32 [32768 + b*512 + c] = c<384 ? h1[b,c] : mu + eps*exp(0.5*lv)
__global__ __launch_bounds__(256) void k_headC3(const float* __restrict__ h1,
    const float* __restrict__ muf, const float* __restrict__ lvf,
    const float* __restrict__ eps, float* __restrict__ out)
{
  int idx = blockIdx.x*256 + threadIdx.x;        // < 65536
  int b = idx >> 9, c = idx & 511;
  float v;
  if(c < Hn){
    v = h1[b*Hn + c];
  } else {
    int zc = c - Hn;
    v = muf[b*Zn + zc] + eps[b*Zn + zc] * expf(0.5f * lvf[b*Zn + zc]);
  }
  out[32768 + idx] = v;
}

extern "C" void kernel_launch(void* const* d_in, const int* in_sizes, int n_in,
                              void* d_out, int out_size, void* d_ws, size_t ws_size,
                              hipStream_t stream) {
  const int*   seq   = (const int*)d_in[0];
  const float* eps   = (const float*)d_in[1];
  const float* embed = (const float*)d_in[2];
  const float* Wih0  = (const float*)d_in[3];
  const float* Whh0  = (const float*)d_in[4];
  const float* Wih1  = (const float*)d_in[5];
  const float* Whh1  = (const float*)d_in[6];
  const float* W1    = (const float*)d_in[7];
  const float* b1    = (const float*)d_in[8];
  const float* Wmu   = (const float*)d_in[9];
  const float* bmu   = (const float*)d_in[10];
  const float* Wlv   = (const float*)d_in[11];
  const float* blv   = (const float*)d_in[12];
  float* out = (float*)d_out;

  char* ws = (char*)d_ws;
  size_t off = 0;
  auto alloc = [&](size_t bytes)->void*{
    void* p = ws + off; off += (bytes + 255) & ~(size_t)255; return p;
  };
  float* h0a = (float*)alloc(196608);
  float* h0b = (float*)alloc(196608);
  float* h1a = (float*)alloc(196608);
  float* h1b = (float*)alloc(196608);
  float* c0s = (float*)alloc(196608);
  float* c1s = (float*)alloc(196608);
  int*   act = (int*)alloc(NSTEPS * sizeof(int));
  float* hv  = (float*)alloc(131072);
  float* muf = (float*)alloc(65536);
  float* lvf = (float*)alloc(65536);
  (void)ws_size; (void)in_sizes; (void)n_in; (void)out_size;

  // zero-init initial state (ws is re-poisoned before every timed launch)
  hipMemsetAsync(h0a, 0, 196608, stream);
  hipMemsetAsync(h1a, 0, 196608, stream);
  hipMemsetAsync(c0s, 0, 196608, stream);
  hipMemsetAsync(c1s, 0, 196608, stream);

  k_act<<<1, 128, 0, stream>>>(seq, act);
  for(int k = 0; k < NSTEPS + 1; ++k)
    k_stepV<<<384, 256, 0, stream>>>(k, seq, embed, Wih0, Whh0, Wih1, Whh1,
                                     h0a, h0b, h1a, h1b, c0s, c1s, act);
  // final h1(s=126, even) is in h1b
  k_headAV<<<128, 256, 0, stream>>>(h1b, W1, b1, hv);
  k_headB3<<<128, 256, 0, stream>>>(hv, Wmu, bmu, Wlv, blv, muf, lvf, out);
  k_headC3<<<256, 256, 0, stream>>>(h1b, muf, lvf, eps, out);
}

// Round 12
// 8218.955 us; speedup vs baseline: 1.4889x; 1.4889x over previous
//
#include <hip/hip_runtime.h>
#include <stdint.h>

#define Bn 128
#define Tn 128
#define En 512
#define Hn 384
#define Zn 128
#define ZHn 256
#define NSTEPS 127

typedef float f32x4 __attribute__((ext_vector_type(4)));

__device__ __forceinline__ float sigm(float x){ return 1.0f/(1.0f + expf(-x)); }

__device__ __forceinline__ float dot1(const float* __restrict__ x,
    const float* __restrict__ w, int K)
{
  float a = 0.f;
  for(int kk = 0; kk < K; kk += 4){
    f32x4 xv = *(const f32x4*)(x + kk);
    f32x4 wv = *(const f32x4*)(w + kk);
    #pragma unroll
    for(int e = 0; e < 4; ++e) a += xv[e] * wv[e];
  }
  return a;
}

// ---------------- sticky active flag: active(s) = all columns t'<=s+1 nonzero ----
__global__ __launch_bounds__(128) void k_act(const int* __restrict__ seq,
                                             int* __restrict__ act)
{
  __shared__ int nz[128];
  int t = threadIdx.x;
  if(t >= 1){
    long long s = 0;
    for(int b = 0; b < Bn; ++b) s += seq[b*Tn + t];
    nz[t] = (s != 0);
  }
  __syncthreads();
  if(t == 0){
    int sticky = 1;
    for(int s = 0; s < NSTEPS; ++s){ sticky = sticky && nz[s+1]; act[s] = sticky; }
  }
}

// ---------------- pipelined step: L0(k) on WGs 0..191, L1(k-1) on 192..383 ------
// WG: 128 batches x 2 units. x staged in LDS per 32-k chunk (coalesced, dbuf).
__global__ __launch_bounds__(256) void k_stepW(int k, const int* __restrict__ seq,
    const float* __restrict__ embed,
    const float* __restrict__ Wih0, const float* __restrict__ Whh0,
    const float* __restrict__ Wih1, const float* __restrict__ Whh1,
    float* __restrict__ h0a, float* __restrict__ h0b,
    float* __restrict__ h1a, float* __restrict__ h1b,
    float* __restrict__ c0s, float* __restrict__ c1s,
    const int* __restrict__ act)
{
  __shared__ float xs[2][128][33];               // 33: bank-conflict-free pad
  int wg = blockIdx.x;
  int isL1 = wg >= 192;
  int lu = isL1 ? wg - 192 : wg;
  int tid = threadIdx.x;
  int b = tid & 127;
  int j = lu*2 + (tid >> 7);
  int s = isL1 ? k - 1 : k;
  if (s < 0 || s >= NSTEPS) return;

  const float *hin0, *hin1 = nullptr;
  float *hout; float* cbuf;
  if(!isL1){
    int p = s & 1;                 // h0(even s)->h0b, h0(odd s)->h0a
    hin0 = p ? h0b : h0a;          // h0(s-1)
    hout = p ? h0a : h0b;          // h0(s)
    cbuf = c0s;
  } else {
    hin0 = (k & 1) ? h0b : h0a;    // nh0(s), written by previous launch's L0
    int q = s & 1;
    hin1 = q ? h1b : h1a;          // h1(s-1)
    hout = q ? h1a : h1b;          // h1(s)
    cbuf = c1s;
  }

  if(!act[s]){
    const float* src = isL1 ? hin1 : hin0;   // freeze: carry state forward
    hout[b*Hn + j] = src[b*Hn + j];
    return;
  }

  // per-thread staging identity: row b2, 16-float half ho
  int b2 = tid >> 1;
  int ho = (tid & 1) * 16;
  int tk2 = 0;
  if(!isL1){
    tk2 = seq[b2*Tn + (s+1)];
    if((unsigned)tk2 > 30000u) tk2 = 0;
  }

  auto stage = [&](int c, int bufi){
    int k0 = c*32 + ho;
    const float* src;
    if(!isL1){
      if(k0 < En) src = embed + (size_t)tk2*En + k0;
      else        src = hin0 + b2*Hn + (k0 - En);
    } else {
      if(k0 < Hn) src = hin0 + b2*Hn + k0;
      else        src = hin1 + b2*Hn + (k0 - Hn);
    }
    f32x4 v0 = *(const f32x4*)(src);
    f32x4 v1 = *(const f32x4*)(src + 4);
    f32x4 v2 = *(const f32x4*)(src + 8);
    f32x4 v3 = *(const f32x4*)(src + 12);
    float* d = &xs[bufi][b2][ho];
    #pragma unroll
    for(int e=0;e<4;e++){ d[e]=v0[e]; d[4+e]=v1[e]; d[8+e]=v2[e]; d[12+e]=v3[e]; }
  };

  int nch = isL1 ? 24 : 28;                     // K = 768 / 896
  int K1len = isL1 ? Hn : En;                   // first-region length
  const float* W1p = isL1 ? Wih1 : Wih0;
  const float* W2p = isL1 ? Whh1 : Whh0;

  float a0 = 0.f, a1 = 0.f, a2 = 0.f, a3 = 0.f;   // gates i,f,g,o

  stage(0, 0);
  __syncthreads();
  for(int c = 0; c < nch; ++c){
    if(c+1 < nch) stage(c+1, (c+1)&1);
    int k0c = c*32;
    const float* wr0; const float* wr1; const float* wr2; const float* wr3;
    if(k0c < K1len){
      wr0 = W1p + (size_t)(0*Hn + j)*K1len + k0c;
      wr1 = W1p + (size_t)(1*Hn + j)*K1len + k0c;
      wr2 = W1p + (size_t)(2*Hn + j)*K1len + k0c;
      wr3 = W1p + (size_t)(3*Hn + j)*K1len + k0c;
    } else {
      int k2 = k0c - K1len;
      wr0 = W2p + (size_t)(0*Hn + j)*Hn + k2;
      wr1 = W2p + (size_t)(1*Hn + j)*Hn + k2;
      wr2 = W2p + (size_t)(2*Hn + j)*Hn + k2;
      wr3 = W2p + (size_t)(3*Hn + j)*Hn + k2;
    }
    const float* xrow = &xs[c&1][b][0];
    #pragma unroll
    for(int kk = 0; kk < 32; kk += 4){
      f32x4 w0 = *(const f32x4*)(wr0 + kk);
      f32x4 w1 = *(const f32x4*)(wr1 + kk);
      f32x4 w2 = *(const f32x4*)(wr2 + kk);
      f32x4 w3 = *(const f32x4*)(wr3 + kk);
      #pragma unroll
      for(int e = 0; e < 4; ++e){
        float xf = xrow[kk + e];
        a0 += xf * w0[e];
        a1 += xf * w1[e];
        a2 += xf * w2[e];
        a3 += xf * w3[e];
      }
    }
    __syncthreads();
  }

  float cp = cbuf[b*Hn + j];
  float cc = sigm(a1)*cp + sigm(a0)*tanhf(a2);
  float hh = sigm(a3)*tanhf(cc);
  cbuf[b*Hn + j] = cc;
  hout[b*Hn + j] = hh;
}

// ---------------- VAE head: hv = relu(h1 @ W1^T + b1) ----------------
__global__ __launch_bounds__(256) void k_headAV(const float* __restrict__ h1,
    const float* __restrict__ W1, const float* __restrict__ b1,
    float* __restrict__ hv)
{
  int tid = threadIdx.x;
  int b = tid & 127;
  int col = blockIdx.x*2 + (tid >> 7);           // 0..255
  float a = dot1(h1 + b*Hn, W1 + (size_t)col*Hn, Hn) + b1[col];
  hv[b*ZHn + col] = a > 0.f ? a : 0.f;
}

// mu -> out f32 [0:16384), lv -> out f32 [16384:32768); also f32 scratch for z
__global__ __launch_bounds__(256) void k_headB3(const float* __restrict__ hv,
    const float* __restrict__ Wmu, const float* __restrict__ bmu,
    const float* __restrict__ Wlv, const float* __restrict__ blv,
    float* __restrict__ muf, float* __restrict__ lvf, float* __restrict__ out)
{
  int tid = threadIdx.x;
  int b = tid & 127;
  int o = blockIdx.x*2 + (tid >> 7);             // 0..255: [0,128)=mu, rest lv
  int head = o >> 7, hr = o & 127;
  const float* W = head ? Wlv : Wmu;
  float a = dot1(hv + b*ZHn, W + (size_t)hr*ZHn, ZHn) + (head ? blv : bmu)[hr];
  if(head){ lvf[b*Zn + hr] = a; out[16384 + b*Zn + hr] = a; }
  else    { muf[b*Zn + hr] = a; out[         b*Zn + hr] = a; }
}

// concat: out f32 [32768 + b*512 + c] = c<384 ? h1[b,c] : mu + eps*exp(0.5*lv)
__global__ __launch_bounds__(256) void k_headC3(const float* __restrict__ h1,
    const float* __restrict__ muf, const float* __restrict__ lvf,
    const float* __restrict__ eps, float* __restrict__ out)
{
  int idx = blockIdx.x*256 + threadIdx.x;        // < 65536
  int b = idx >> 9, c = idx & 511;
  float v;
  if(c < Hn){
    v = h1[b*Hn + c];
  } else {
    int zc = c - Hn;
    v = muf[b*Zn + zc] + eps[b*Zn + zc] * expf(0.5f * lvf[b*Zn + zc]);
  }
  out[32768 + idx] = v;
}

extern "C" void kernel_launch(void* const* d_in, const int* in_sizes, int n_in,
                              void* d_out, int out_size, void* d_ws, size_t ws_size,
                              hipStream_t stream) {
  const int*   seq   = (const int*)d_in[0];
  const float* eps   = (const float*)d_in[1];
  const float* embed = (const float*)d_in[2];
  const float* Wih0  = (const float*)d_in[3];
  const float* Whh0  = (const float*)d_in[4];
  const float* Wih1  = (const float*)d_in[5];
  const float* Whh1  = (const float*)d_in[6];
  const float* W1    = (const float*)d_in[7];
  const float* b1    = (const float*)d_in[8];
  const float* Wmu   = (const float*)d_in[9];
  const float* bmu   = (const float*)d_in[10];
  const float* Wlv   = (const float*)d_in[11];
  const float* blv   = (const float*)d_in[12];
  float* out = (float*)d_out;

  char* ws = (char*)d_ws;
  size_t off = 0;
  auto alloc = [&](size_t bytes)->void*{
    void* p = ws + off; off += (bytes + 255) & ~(size_t)255; return p;
  };
  float* h0a = (float*)alloc(196608);
  float* h0b = (float*)alloc(196608);
  float* h1a = (float*)alloc(196608);
  float* h1b = (float*)alloc(196608);
  float* c0s = (float*)alloc(196608);
  float* c1s = (float*)alloc(196608);
  int*   act = (int*)alloc(NSTEPS * sizeof(int));
  float* hv  = (float*)alloc(131072);
  float* muf = (float*)alloc(65536);
  float* lvf = (float*)alloc(65536);
  (void)ws_size; (void)in_sizes; (void)n_in; (void)out_size;

  // zero-init initial state (ws is re-poisoned before every timed launch)
  hipMemsetAsync(h0a, 0, 196608, stream);
  hipMemsetAsync(h1a, 0, 196608, stream);
  hipMemsetAsync(c0s, 0, 196608, stream);
  hipMemsetAsync(c1s, 0, 196608, stream);

  k_act<<<1, 128, 0, stream>>>(seq, act);
  for(int k = 0; k < NSTEPS + 1; ++k)
    k_stepW<<<384, 256, 0, stream>>>(k, seq, embed, Wih0, Whh0, Wih1, Whh1,
                                     h0a, h0b, h1a, h1b, c0s, c1s, act);
  // final h1(s=126, even) is in h1b
  k_headAV<<<128, 256, 0, stream>>>(h1b, W1, b1, hv);
  k_headB3<<<128, 256, 0, stream>>>(hv, Wmu, bmu, Wlv, blv, muf, lvf, out);
  k_headC3<<<256, 256, 0, stream>>>(h1b, muf, lvf, eps, out);
}